// Round 2
// baseline (289.632 us; speedup 1.0000x reference)
//
#include <hip/hip_runtime.h>

// ---------------------------------------------------------------------------
// QTranBase: twin 3-layer MLPs via bf16 MFMA.
// R8: fix R7's race. R7's counted vmcnt(4) assumed phase p reads only
// half-tiles staged first; but im=1 / in>=2 waves read half-1 rows in
// phase 0 -> read-before-DMA-landed race (absmax 0.105). Since every wave
// stages data other waves read, each wave MUST drain its own gload_lds to
// vmcnt(0) before the publishing barrier. Sound schedule: issue all 8
// next-tile loads at phases 0-2, single vmcnt(0) after phase 3's MFMA
// cluster (loads get ~3 phases of cover), one drain per 64-K-tile.
// Swizzle (T2 both-sides), setprio (T5), XCD swizzle, prep unchanged.
// ---------------------------------------------------------------------------

#define ROWS 32768
#define EMBED 512

using frag_ab = __attribute__((ext_vector_type(8))) short;   // 8 x bf16
using f32x4   = __attribute__((ext_vector_type(4))) float;   // MFMA C/D

__device__ __forceinline__ unsigned short f2bf(float f) {
    unsigned int u = __builtin_bit_cast(unsigned int, f);
    return (unsigned short)((u + 0x7fffu + ((u >> 16) & 1u)) >> 16);
}

__device__ __forceinline__ unsigned pk2rne(float lo, float hi) {
    return (unsigned)f2bf(lo) | ((unsigned)f2bf(hi) << 16);
}

__device__ __forceinline__ void async_copy16(const void* g, void* l) {
    // dest = wave-uniform LDS base; HW writes base + lane*16 (linear!)
    __builtin_amdgcn_global_load_lds(
        (const __attribute__((address_space(1))) unsigned int*)g,
        (__attribute__((address_space(3))) unsigned int*)l, 16, 0, 0);
}

#define VM0()   asm volatile("s_waitcnt vmcnt(0)" ::: "memory")
#define LGKM0() asm volatile("s_waitcnt lgkmcnt(0)" ::: "memory")
#define SBAR()  __builtin_amdgcn_s_barrier()
#define SCHED0() __builtin_amdgcn_sched_barrier(0)

// ---------------------------------------------------------------------------
// Fused prep: blocks [0,4096) convert X; [4096,4416) transpose weights via
// LDS tiles (coalesced both sides); [4416,4672) seed out with layer-3 bias.
// ---------------------------------------------------------------------------
__global__ __launch_bounds__(256)
void prep(const float* __restrict__ states, const float* __restrict__ actions,
          const float* __restrict__ Qw1, const float* __restrict__ Qw2,
          const float* __restrict__ Vw1, const float* __restrict__ Vw2,
          const float* __restrict__ qb3, const float* __restrict__ vb3,
          unsigned short* __restrict__ X,
          unsigned short* __restrict__ Qw1t, unsigned short* __restrict__ Qw2t,
          unsigned short* __restrict__ Vw1t, unsigned short* __restrict__ Vw2t,
          float* __restrict__ out) {
    const int b = blockIdx.x, tid = threadIdx.x;
    if (b < 4096) {
        int c = b * 256 + tid;            // chunk of 32 within one row
        int m = c >> 5, col = (c & 31) * 32;
        const float* src = (col < 512) ? states + (size_t)m * 512 + col
                                       : actions + (size_t)m * 512 + (col - 512);
        float4 f[8];
#pragma unroll
        for (int i = 0; i < 8; i++) f[i] = ((const float4*)src)[i];
        uint4* dst = (uint4*)(X + (size_t)m * 1024 + col);
#pragma unroll
        for (int i = 0; i < 4; i++)
            dst[i] = make_uint4(pk2rne(f[2*i].x,   f[2*i].y),
                                pk2rne(f[2*i].z,   f[2*i].w),
                                pk2rne(f[2*i+1].x, f[2*i+1].y),
                                pk2rne(f[2*i+1].z, f[2*i+1].w));
    } else if (b < 4416) {
        // 64x64 f32 tile transpose through LDS (+1 pad -> conflict-free cols)
        __shared__ float T[64][65];
        int tg = b - 4096;
        const float* W; unsigned short* O; int Krows, kt, nt;
        if (tg < 128) { W = Qw1; O = Qw1t; Krows = 1024; kt = tg >> 3; nt = tg & 7; }
        else {
            tg -= 128; int seg = tg >> 6, r = tg & 63;
            kt = r >> 3; nt = r & 7; Krows = 512;
            W = (seg == 0) ? Qw2 : (seg == 1) ? Vw1 : Vw2;
            O = (seg == 0) ? Qw2t : (seg == 1) ? Vw1t : Vw2t;
        }
        const int k0 = kt * 64, n0 = nt * 64;
        const int rr = tid >> 4, c4 = (tid & 15) * 4;
#pragma unroll
        for (int p = 0; p < 4; ++p) {
            float4 v = *(const float4*)&W[(size_t)(k0 + p * 16 + rr) * 512 + n0 + c4];
            T[p * 16 + rr][c4]     = v.x;
            T[p * 16 + rr][c4 + 1] = v.y;
            T[p * 16 + rr][c4 + 2] = v.z;
            T[p * 16 + rr][c4 + 3] = v.w;
        }
        __syncthreads();
        const int n = tid >> 2, kc = (tid & 3) * 16;
        unsigned pk[8];
#pragma unroll
        for (int j = 0; j < 8; ++j)
            pk[j] = pk2rne(T[kc + 2 * j][n], T[kc + 2 * j + 1][n]);
        uint4* dst = (uint4*)(O + (size_t)(n0 + n) * Krows + k0 + kc);
        dst[0] = make_uint4(pk[0], pk[1], pk[2], pk[3]);
        dst[1] = make_uint4(pk[4], pk[5], pk[6], pk[7]);
    } else {
        int i = (b - 4416) * 256 + tid;
        out[i] = (i < ROWS) ? qb3[0] : vb3[0];
    }
}

// ---------------------------------------------------------------------------
// 256x256 8-wave GEMM mainloop, 4 phases per 64-wide K-tile. BK=64, double-
// buffered LDS. Layout per operand: [buf][half(128 rows)][row 128B], A at 0,
// B at 64KB. Swizzle (T2, rule #21 both-sides): linear gload_lds dest +
// inverse-swizzled global source + swizzled ds_read: col16' = col16^(row&7).
// Wait schedule (sound for all-waves-stage-all): next-tile loads issued at
// phases 0-2; single own-loads vmcnt(0) after phase 3's MFMAs, before the
// tile-boundary barrier that publishes the buffer.
// ---------------------------------------------------------------------------
__device__ __forceinline__ void gemm_256(
    const unsigned short* __restrict__ A, int ldaE,
    const unsigned short* __restrict__ Bt, int ldbE,
    int K, int bm, int bn, char* smb, f32x4 acc[8][4])
{
    const int tid = threadIdx.x, wave = tid >> 6, lane = tid & 63;
    const int im = wave >> 2, in = wave & 3;        // 2M x 4N waves
    const int lrow = lane & 15, quad = lane >> 4;
    const int ldaB = ldaE * 2, ldbB = ldbE * 2;

    // staging: wave w, lane l covers LDS bytes [w*1024 + l*16) per issue;
    // row = w*8 + (l>>3), col16 = l&7; global source pre-swizzled.
    const int srow = wave * 8 + (lane >> 3);
    const int scol = (((lane & 7) ^ ((lane >> 3) & 7)) << 4);
    const char* gA = (const char*)A + (size_t)(bm + srow) * ldaB + scol;
    const char* gB = (const char*)Bt + (size_t)(bn + srow) * ldbB + scol;
    char* ldsAw = smb + wave * 1024;
    char* ldsBw = smb + 65536 + wave * 1024;

    auto stageA = [&](int b, int h) {
        const char* g = gA + (size_t)(h * 128) * ldaB;
        char* l = ldsAw + b * 32768 + h * 16384;
        async_copy16(g, l);
        async_copy16(g + (size_t)64 * ldaB, l + 8192);
    };
    auto stageB = [&](int b, int h) {
        const char* g = gB + (size_t)(h * 128) * ldbB;
        char* l = ldsBw + b * 32768 + h * 16384;
        async_copy16(g, l);
        async_copy16(g + (size_t)64 * ldbB, l + 8192);
    };

    frag_ab a[4][2], b0[2][2], b1[2][2];

    auto readA = [&](int b, int mh) {
        const char* base = smb + b * 32768 + im * 16384;
#pragma unroll
        for (int i = 0; i < 4; ++i) {
            const int r = mh * 64 + i * 16 + lrow;    // row within 128-half
#pragma unroll
            for (int s = 0; s < 2; ++s)
                a[i][s] = *(const frag_ab*)(base + r * 128 +
                              (((s * 4 + quad) ^ (r & 7)) << 4));
        }
    };
    auto readB = [&](int b, int nh, frag_ab bb[2][2]) {
#pragma unroll
        for (int j = 0; j < 2; ++j) {
            const int nr = in * 64 + nh * 32 + j * 16 + lrow;   // 0..255
            const char* base = smb + 65536 + b * 32768 + (nr >> 7) * 16384;
            const int r = nr & 127;
#pragma unroll
            for (int s = 0; s < 2; ++s)
                bb[j][s] = *(const frag_ab*)(base + r * 128 +
                               (((s * 4 + quad) ^ (r & 7)) << 4));
        }
    };
    auto mma = [&](int mh, int nh, frag_ab bb[2][2]) {
        __builtin_amdgcn_s_setprio(1);
#pragma unroll
        for (int s = 0; s < 2; ++s)
#pragma unroll
            for (int i = 0; i < 4; ++i)
#pragma unroll
                for (int j = 0; j < 2; ++j)
                    acc[mh * 4 + i][nh * 2 + j] =
                        __builtin_amdgcn_mfma_f32_16x16x32_bf16(
                            a[i][s], bb[j][s], acc[mh * 4 + i][nh * 2 + j],
                            0, 0, 0);
        __builtin_amdgcn_s_setprio(0);
    };

    // prologue: tile 0 -> buf 0 (8 loads), full drain + publish.
    stageA(0, 0); stageB(0, 0); stageB(0, 1); stageA(0, 1);
    gA += 128; gB += 128;
    VM0();
    SBAR();

    const int NT = K >> 6;
    int buf = 0;
    for (int t = 0; t < NT; ++t) {
        const bool more = (t + 1 < NT);
        const int nb = buf ^ 1;
        // phase 0: quadrant (0,0); issue next-tile A0,B0 (4 loads)
        readA(buf, 0); readB(buf, 0, b0);
        if (more) { stageA(nb, 0); stageB(nb, 0); }
        SBAR(); LGKM0(); SCHED0();
        mma(0, 0, b0);
        SBAR();
        // phase 1: quadrant (0,1); issue next-tile B1 (2 loads)
        readB(buf, 1, b1);
        if (more) stageB(nb, 1);
        SBAR(); LGKM0(); SCHED0();
        mma(0, 1, b1);
        SBAR();
        // phase 2: quadrant (1,1); issue next-tile A1 (2 loads)
        readA(buf, 1);
        if (more) { stageA(nb, 1); gA += 128; gB += 128; }
        SBAR(); LGKM0(); SCHED0();
        mma(1, 1, b1);
        SBAR();
        // phase 3: quadrant (1,0); drain own loads AFTER the MFMAs, then
        // the boundary barrier publishes buf^1 for next tile's reads.
        SBAR(); LGKM0(); SCHED0();
        mma(1, 0, b0);
        if (more) VM0();
        SBAR();
        buf ^= 1;
    }
}

// 512 blocks: bijective XCD swizzle (512 = 8*64); work = mi*4 + variant so
// the 4 same-mi variants (Qn0,Qn1,Vn0,Vn1) land on one XCD's L2.
__device__ __forceinline__ void decode_work(int bid, int& mi, int& v) {
    int work = ((bid & 7) << 6) | (bid >> 3);
    mi = work >> 2; v = work & 3;
}

// ---------------------------------------------------------------------------
// Layer 1 (Q+V): h1 = relu(X @ Wt^T + bias). v<2 -> Q (K=1024), else V (512).
// ---------------------------------------------------------------------------
__global__ __launch_bounds__(512, 2)
void layer1(const unsigned short* __restrict__ X,
            const unsigned short* __restrict__ Qw1t,
            const unsigned short* __restrict__ Vw1t,
            const float* __restrict__ Qb1, const float* __restrict__ Vb1,
            unsigned short* __restrict__ h1Q, unsigned short* __restrict__ h1V) {
    __shared__ __align__(16) char smem[131072];
    int mi, v; decode_work(blockIdx.x, mi, v);
    const bool isV = v >= 2;
    const int bm = mi * 256, bn = (v & 1) * 256;
    const int K = isV ? 512 : 1024;
    const unsigned short* Wt = isV ? Vw1t : Qw1t;
    const float* bias = isV ? Vb1 : Qb1;
    unsigned short* H = isV ? h1V : h1Q;

    f32x4 acc[8][4] = {};
    gemm_256(X, 1024, Wt, K, K, bm, bn, smem, acc);

    const int tid = threadIdx.x, wave = tid >> 6, lane = tid & 63;
    const int im = wave >> 2, in = wave & 3;
    const int lrow = lane & 15, quad = lane >> 4;
#pragma unroll
    for (int j = 0; j < 4; ++j) {
        const int col = bn + in * 64 + j * 16 + lrow;
        const float bc = bias[col];
#pragma unroll
        for (int i = 0; i < 8; ++i) {
            const int row0 = bm + im * 128 + i * 16 + quad * 4;
#pragma unroll
            for (int r = 0; r < 4; ++r) {
                float val = acc[i][j][r] + bc;
                val = val > 0.0f ? val : 0.0f;
                H[(size_t)(row0 + r) * EMBED + col] = f2bf(val);
            }
        }
    }
}

// ---------------------------------------------------------------------------
// Layer 2+3 (Q+V): out[row] += sum_n relu(h1 @ W2^T + b2)[n] * w3[n]
// ---------------------------------------------------------------------------
__global__ __launch_bounds__(512, 2)
void layer2(const unsigned short* __restrict__ h1Q,
            const unsigned short* __restrict__ h1V,
            const unsigned short* __restrict__ Qw2t,
            const unsigned short* __restrict__ Vw2t,
            const float* __restrict__ Qb2, const float* __restrict__ Vb2,
            const float* __restrict__ Qw3, const float* __restrict__ Vw3,
            float* __restrict__ out) {
    __shared__ __align__(16) char smem[131072];
    int mi, v; decode_work(blockIdx.x, mi, v);
    const bool isV = v >= 2;
    const int bm = mi * 256, bn = (v & 1) * 256;
    const unsigned short* A  = isV ? h1V : h1Q;
    const unsigned short* Wt = isV ? Vw2t : Qw2t;
    const float* bias = isV ? Vb2 : Qb2;
    const float* w3   = isV ? Vw3 : Qw3;
    float* op = out + (isV ? ROWS : 0);

    f32x4 acc[8][4] = {};
    gemm_256(A, 512, Wt, 512, 512, bm, bn, smem, acc);

    const int tid = threadIdx.x, wave = tid >> 6, lane = tid & 63;
    const int im = wave >> 2, in = wave & 3;
    const int lrow = lane & 15, quad = lane >> 4;
    float bc[4], wc[4];
#pragma unroll
    for (int j = 0; j < 4; ++j) {
        const int col = bn + in * 64 + j * 16 + lrow;
        bc[j] = bias[col];
        wc[j] = w3[col];
    }
#pragma unroll
    for (int i = 0; i < 8; ++i) {
#pragma unroll
        for (int r = 0; r < 4; ++r) {
            float s = 0.0f;
#pragma unroll
            for (int j = 0; j < 4; ++j) {
                float val = acc[i][j][r] + bc[j];
                val = val > 0.0f ? val : 0.0f;
                s += val * wc[j];
            }
#pragma unroll
            for (int m = 1; m < 16; m <<= 1) s += __shfl_xor(s, m, 64);
            if (lrow == 0)
                atomicAdd(&op[bm + im * 128 + i * 16 + quad * 4 + r], s);
        }
    }
}

extern "C" void kernel_launch(void* const* d_in, const int* in_sizes, int n_in,
                              void* d_out, int out_size, void* d_ws, size_t ws_size,
                              hipStream_t stream) {
    const float* states  = (const float*)d_in[0];
    const float* actions = (const float*)d_in[1];
    const float* Qw1 = (const float*)d_in[2];
    const float* Qb1 = (const float*)d_in[3];
    const float* Qw2 = (const float*)d_in[4];
    const float* Qb2 = (const float*)d_in[5];
    const float* Qw3 = (const float*)d_in[6];
    const float* Qb3 = (const float*)d_in[7];
    const float* Vw1 = (const float*)d_in[8];
    const float* Vb1 = (const float*)d_in[9];
    const float* Vw2 = (const float*)d_in[10];
    const float* Vb2 = (const float*)d_in[11];
    const float* Vw3 = (const float*)d_in[12];
    const float* Vb3 = (const float*)d_in[13];
    float* out = (float*)d_out;

    // workspace layout (bytes)
    char* ws = (char*)d_ws;
    unsigned short* X    = (unsigned short*)ws;                        // 64 MB
    unsigned short* h1Q  = (unsigned short*)(ws + 67108864);           // 32 MB
    unsigned short* h1V  = (unsigned short*)(ws + 100663296);          // 32 MB
    unsigned short* Qw1t = (unsigned short*)(ws + 134217728);          // 1 MB
    unsigned short* Qw2t = Qw1t + 512 * 1024;
    unsigned short* Vw1t = Qw2t + 512 * 512;
    unsigned short* Vw2t = Vw1t + 512 * 512;

    prep<<<dim3(4672), dim3(256), 0, stream>>>(states, actions, Qw1, Qw2, Vw1, Vw2,
                                               Qb3, Vb3, X, Qw1t, Qw2t, Vw1t, Vw2t, out);

    layer1<<<dim3(512), dim3(512), 0, stream>>>(X, Qw1t, Vw1t, Qb1, Vb1, h1Q, h1V);
    layer2<<<dim3(512), dim3(512), 0, stream>>>(h1Q, h1V, Qw2t, Vw2t, Qb2, Vb2, Qw3, Vw3, out);
}

// Round 3
// 283.046 us; speedup vs baseline: 1.0233x; 1.0233x over previous
//
#include <hip/hip_runtime.h>

// ---------------------------------------------------------------------------
// QTranBase: twin 3-layer MLPs via bf16 MFMA.
// R9: whole-tile counted-vmcnt pipeline. R8 post-mortem: swizzle killed all
// bank conflicts (4.7M->0) but 8 barriers/tile + vmcnt(0) drain at 1
// block/CU (128KB LDS) regressed. Since every phase reads all half-tiles
// (spatial wave grid), half-tile counted vmcnt is unsound -- but WHOLE-TILE
// is: dbuf, stage(t+1) issued during tile t, drained with vmcnt(8) at tile
// t+1 entry (one full tile of cover), stage(t+2) issued after the closing
// barrier. 2 barriers + 1 counted wait per 64-K tile, no mid-tile barriers,
// compiler-scheduled ds_read/MFMA interleave. Also: coalesced prep convert.
// ---------------------------------------------------------------------------

#define ROWS 32768
#define EMBED 512

using frag_ab = __attribute__((ext_vector_type(8))) short;   // 8 x bf16
using f32x4   = __attribute__((ext_vector_type(4))) float;   // MFMA C/D

__device__ __forceinline__ unsigned short f2bf(float f) {
    unsigned int u = __builtin_bit_cast(unsigned int, f);
    return (unsigned short)((u + 0x7fffu + ((u >> 16) & 1u)) >> 16);
}

__device__ __forceinline__ unsigned pk2rne(float lo, float hi) {
    return (unsigned)f2bf(lo) | ((unsigned)f2bf(hi) << 16);
}

__device__ __forceinline__ void async_copy16(const void* g, void* l) {
    // dest = wave-uniform LDS base; HW writes base + lane*16 (linear!)
    __builtin_amdgcn_global_load_lds(
        (const __attribute__((address_space(1))) unsigned int*)g,
        (__attribute__((address_space(3))) unsigned int*)l, 16, 0, 0);
}

#define VM8()   asm volatile("s_waitcnt vmcnt(8)" ::: "memory")
#define VM0()   asm volatile("s_waitcnt vmcnt(0)" ::: "memory")
#define SBAR()  __builtin_amdgcn_s_barrier()

// ---------------------------------------------------------------------------
// Fused prep: blocks [0,16384) convert X (coalesced: 8 consecutive f32 per
// thread); [16384,16704) transpose weights via LDS tiles; [16704,16960)
// seed out with layer-3 bias.
// ---------------------------------------------------------------------------
__global__ __launch_bounds__(256)
void prep(const float* __restrict__ states, const float* __restrict__ actions,
          const float* __restrict__ Qw1, const float* __restrict__ Qw2,
          const float* __restrict__ Vw1, const float* __restrict__ Vw2,
          const float* __restrict__ qb3, const float* __restrict__ vb3,
          unsigned short* __restrict__ X,
          unsigned short* __restrict__ Qw1t, unsigned short* __restrict__ Qw2t,
          unsigned short* __restrict__ Vw1t, unsigned short* __restrict__ Vw2t,
          float* __restrict__ out) {
    const int b = blockIdx.x, tid = threadIdx.x;
    if (b < 16384) {
        // group g: 8 consecutive elems of X row (row-major [32768][1024]).
        int g = b * 256 + tid;
        int m = g >> 7, col = (g & 127) * 8;
        const float* src = (col < 512) ? states + (size_t)m * 512 + col
                                       : actions + (size_t)m * 512 + (col - 512);
        float4 f0 = ((const float4*)src)[0];
        float4 f1 = ((const float4*)src)[1];
        *(uint4*)(X + (size_t)m * 1024 + col) =
            make_uint4(pk2rne(f0.x, f0.y), pk2rne(f0.z, f0.w),
                       pk2rne(f1.x, f1.y), pk2rne(f1.z, f1.w));
    } else if (b < 16704) {
        // 64x64 f32 tile transpose through LDS (+1 pad -> conflict-free cols)
        __shared__ float T[64][65];
        int tg = b - 16384;
        const float* W; unsigned short* O; int Krows, kt, nt;
        if (tg < 128) { W = Qw1; O = Qw1t; Krows = 1024; kt = tg >> 3; nt = tg & 7; }
        else {
            tg -= 128; int seg = tg >> 6, r = tg & 63;
            kt = r >> 3; nt = r & 7; Krows = 512;
            W = (seg == 0) ? Qw2 : (seg == 1) ? Vw1 : Vw2;
            O = (seg == 0) ? Qw2t : (seg == 1) ? Vw1t : Vw2t;
        }
        const int k0 = kt * 64, n0 = nt * 64;
        const int rr = tid >> 4, c4 = (tid & 15) * 4;
#pragma unroll
        for (int p = 0; p < 4; ++p) {
            float4 v = *(const float4*)&W[(size_t)(k0 + p * 16 + rr) * 512 + n0 + c4];
            T[p * 16 + rr][c4]     = v.x;
            T[p * 16 + rr][c4 + 1] = v.y;
            T[p * 16 + rr][c4 + 2] = v.z;
            T[p * 16 + rr][c4 + 3] = v.w;
        }
        __syncthreads();
        const int n = tid >> 2, kc = (tid & 3) * 16;
        unsigned pk[8];
#pragma unroll
        for (int j = 0; j < 8; ++j)
            pk[j] = pk2rne(T[kc + 2 * j][n], T[kc + 2 * j + 1][n]);
        uint4* dst = (uint4*)(O + (size_t)(n0 + n) * Krows + k0 + kc);
        dst[0] = make_uint4(pk[0], pk[1], pk[2], pk[3]);
        dst[1] = make_uint4(pk[4], pk[5], pk[6], pk[7]);
    } else {
        int i = (b - 16704) * 256 + tid;
        out[i] = (i < ROWS) ? qb3[0] : vb3[0];
    }
}

// ---------------------------------------------------------------------------
// 256x256 8-wave GEMM mainloop. BK=64, double-buffered LDS (128 KB, 1
// block/CU). Layout per operand: [buf][half(128 rows)][row 128B], A at 0,
// B at 64KB. Swizzle (T2, rule #21 both-sides): linear gload_lds dest +
// inverse-swizzled global source + swizzled ds_read: col16' = col16^(row&7).
// Pipeline (whole-tile counted vmcnt, sound for all-waves-stage-all):
//   prologue: stage(0)->buf0, stage(1)->buf1           [16 outstanding]
//   iter t:   vmcnt(8) [stage(t) landed, stage(t+1) flying]; SBAR;
//             24 ds_read + 32 MFMA (compiler-interleaved, no barriers);
//             SBAR; issue stage(t+2) -> buf[t&1]
// Loads get one full tile (~2000 cy) of cover; one drain per K-tile, never
// to 0 mid-loop (vmcnt(0) only at the last tile).
// ---------------------------------------------------------------------------
__device__ __forceinline__ void gemm_256(
    const unsigned short* __restrict__ A, int ldaE,
    const unsigned short* __restrict__ Bt, int ldbE,
    int K, int bm, int bn, char* smb, f32x4 acc[8][4])
{
    const int tid = threadIdx.x, wave = tid >> 6, lane = tid & 63;
    const int im = wave >> 2, in = wave & 3;        // 2M x 4N waves
    const int lrow = lane & 15, quad = lane >> 4;
    const int ldaB = ldaE * 2, ldbB = ldbE * 2;

    // staging: wave w, lane l covers LDS bytes [w*1024 + l*16) per issue;
    // row = w*8 + (l>>3), col16 = l&7; global source pre-swizzled.
    const int srow = wave * 8 + (lane >> 3);
    const int scol = (((lane & 7) ^ ((lane >> 3) & 7)) << 4);
    const char* gA = (const char*)A + (size_t)(bm + srow) * ldaB + scol;
    const char* gB = (const char*)Bt + (size_t)(bn + srow) * ldbB + scol;
    char* ldsAw = smb + wave * 1024;
    char* ldsBw = smb + 65536 + wave * 1024;

    auto stageTile = [&](int b) {    // 8 vmcnt events per wave
#pragma unroll
        for (int h = 0; h < 2; ++h) {
            const char* g = gA + (size_t)(h * 128) * ldaB;
            char* l = ldsAw + b * 32768 + h * 16384;
            async_copy16(g, l);
            async_copy16(g + (size_t)64 * ldaB, l + 8192);
        }
#pragma unroll
        for (int h = 0; h < 2; ++h) {
            const char* g = gB + (size_t)(h * 128) * ldbB;
            char* l = ldsBw + b * 32768 + h * 16384;
            async_copy16(g, l);
            async_copy16(g + (size_t)64 * ldbB, l + 8192);
        }
        gA += 128; gB += 128;
    };

    frag_ab a[4][2], b0[2][2], b1[2][2];

    auto readA = [&](int b, int mh) {
        const char* base = smb + b * 32768 + im * 16384;
#pragma unroll
        for (int i = 0; i < 4; ++i) {
            const int r = mh * 64 + i * 16 + lrow;    // row within 128-half
#pragma unroll
            for (int s = 0; s < 2; ++s)
                a[i][s] = *(const frag_ab*)(base + r * 128 +
                              (((s * 4 + quad) ^ (r & 7)) << 4));
        }
    };
    auto readB = [&](int b, int nh, frag_ab bb[2][2]) {
#pragma unroll
        for (int j = 0; j < 2; ++j) {
            const int nr = in * 64 + nh * 32 + j * 16 + lrow;   // 0..255
            const char* base = smb + 65536 + b * 32768 + (nr >> 7) * 16384;
            const int r = nr & 127;
#pragma unroll
            for (int s = 0; s < 2; ++s)
                bb[j][s] = *(const frag_ab*)(base + r * 128 +
                               (((s * 4 + quad) ^ (r & 7)) << 4));
        }
    };
    auto mma = [&](int mh, int nh, frag_ab bb[2][2]) {
        __builtin_amdgcn_s_setprio(1);
#pragma unroll
        for (int s = 0; s < 2; ++s)
#pragma unroll
            for (int i = 0; i < 4; ++i)
#pragma unroll
                for (int j = 0; j < 2; ++j)
                    acc[mh * 4 + i][nh * 2 + j] =
                        __builtin_amdgcn_mfma_f32_16x16x32_bf16(
                            a[i][s], bb[j][s], acc[mh * 4 + i][nh * 2 + j],
                            0, 0, 0);
        __builtin_amdgcn_s_setprio(0);
    };

    // prologue: tiles 0 and 1 in flight.
    stageTile(0);
    stageTile(1);

    const int NT = K >> 6;
    int buf = 0;
    for (int t = 0; t < NT; ++t) {
        if (t + 1 < NT) VM8(); else VM0();
        SBAR();                      // buf published; prior reads of it done
        readA(buf, 0); readB(buf, 0, b0);
        mma(0, 0, b0);
        readB(buf, 1, b1);
        mma(0, 1, b1);
        readA(buf, 1);
        mma(1, 1, b1);
        mma(1, 0, b0);
        SBAR();                      // all waves done reading buf
        if (t + 2 < NT) stageTile(buf);   // tile t+2 -> buf[t&1]
        buf ^= 1;
    }
}

// 512 blocks: bijective XCD swizzle (512 = 8*64); work = mi*4 + variant so
// the 4 same-mi variants (Qn0,Qn1,Vn0,Vn1) land on one XCD's L2.
__device__ __forceinline__ void decode_work(int bid, int& mi, int& v) {
    int work = ((bid & 7) << 6) | (bid >> 3);
    mi = work >> 2; v = work & 3;
}

// ---------------------------------------------------------------------------
// Layer 1 (Q+V): h1 = relu(X @ Wt^T + bias). v<2 -> Q (K=1024), else V (512).
// ---------------------------------------------------------------------------
__global__ __launch_bounds__(512, 2)
void layer1(const unsigned short* __restrict__ X,
            const unsigned short* __restrict__ Qw1t,
            const unsigned short* __restrict__ Vw1t,
            const float* __restrict__ Qb1, const float* __restrict__ Vb1,
            unsigned short* __restrict__ h1Q, unsigned short* __restrict__ h1V) {
    __shared__ __align__(16) char smem[131072];
    int mi, v; decode_work(blockIdx.x, mi, v);
    const bool isV = v >= 2;
    const int bm = mi * 256, bn = (v & 1) * 256;
    const int K = isV ? 512 : 1024;
    const unsigned short* Wt = isV ? Vw1t : Qw1t;
    const float* bias = isV ? Vb1 : Qb1;
    unsigned short* H = isV ? h1V : h1Q;

    f32x4 acc[8][4] = {};
    gemm_256(X, 1024, Wt, K, K, bm, bn, smem, acc);

    const int tid = threadIdx.x, wave = tid >> 6, lane = tid & 63;
    const int im = wave >> 2, in = wave & 3;
    const int lrow = lane & 15, quad = lane >> 4;
#pragma unroll
    for (int j = 0; j < 4; ++j) {
        const int col = bn + in * 64 + j * 16 + lrow;
        const float bc = bias[col];
#pragma unroll
        for (int i = 0; i < 8; ++i) {
            const int row0 = bm + im * 128 + i * 16 + quad * 4;
#pragma unroll
            for (int r = 0; r < 4; ++r) {
                float val = acc[i][j][r] + bc;
                val = val > 0.0f ? val : 0.0f;
                H[(size_t)(row0 + r) * EMBED + col] = f2bf(val);
            }
        }
    }
}

// ---------------------------------------------------------------------------
// Layer 2+3 (Q+V): out[row] += sum_n relu(h1 @ W2^T + b2)[n] * w3[n]
// ---------------------------------------------------------------------------
__global__ __launch_bounds__(512, 2)
void layer2(const unsigned short* __restrict__ h1Q,
            const unsigned short* __restrict__ h1V,
            const unsigned short* __restrict__ Qw2t,
            const unsigned short* __restrict__ Vw2t,
            const float* __restrict__ Qb2, const float* __restrict__ Vb2,
            const float* __restrict__ Qw3, const float* __restrict__ Vw3,
            float* __restrict__ out) {
    __shared__ __align__(16) char smem[131072];
    int mi, v; decode_work(blockIdx.x, mi, v);
    const bool isV = v >= 2;
    const int bm = mi * 256, bn = (v & 1) * 256;
    const unsigned short* A  = isV ? h1V : h1Q;
    const unsigned short* Wt = isV ? Vw2t : Qw2t;
    const float* bias = isV ? Vb2 : Qb2;
    const float* w3   = isV ? Vw3 : Qw3;
    float* op = out + (isV ? ROWS : 0);

    f32x4 acc[8][4] = {};
    gemm_256(A, 512, Wt, 512, 512, bm, bn, smem, acc);

    const int tid = threadIdx.x, wave = tid >> 6, lane = tid & 63;
    const int im = wave >> 2, in = wave & 3;
    const int lrow = lane & 15, quad = lane >> 4;
    float bc[4], wc[4];
#pragma unroll
    for (int j = 0; j < 4; ++j) {
        const int col = bn + in * 64 + j * 16 + lrow;
        bc[j] = bias[col];
        wc[j] = w3[col];
    }
#pragma unroll
    for (int i = 0; i < 8; ++i) {
#pragma unroll
        for (int r = 0; r < 4; ++r) {
            float s = 0.0f;
#pragma unroll
            for (int j = 0; j < 4; ++j) {
                float val = acc[i][j][r] + bc[j];
                val = val > 0.0f ? val : 0.0f;
                s += val * wc[j];
            }
#pragma unroll
            for (int m = 1; m < 16; m <<= 1) s += __shfl_xor(s, m, 64);
            if (lrow == 0)
                atomicAdd(&op[bm + im * 128 + i * 16 + quad * 4 + r], s);
        }
    }
}

extern "C" void kernel_launch(void* const* d_in, const int* in_sizes, int n_in,
                              void* d_out, int out_size, void* d_ws, size_t ws_size,
                              hipStream_t stream) {
    const float* states  = (const float*)d_in[0];
    const float* actions = (const float*)d_in[1];
    const float* Qw1 = (const float*)d_in[2];
    const float* Qb1 = (const float*)d_in[3];
    const float* Qw2 = (const float*)d_in[4];
    const float* Qb2 = (const float*)d_in[5];
    const float* Qw3 = (const float*)d_in[6];
    const float* Qb3 = (const float*)d_in[7];
    const float* Vw1 = (const float*)d_in[8];
    const float* Vb1 = (const float*)d_in[9];
    const float* Vw2 = (const float*)d_in[10];
    const float* Vb2 = (const float*)d_in[11];
    const float* Vw3 = (const float*)d_in[12];
    const float* Vb3 = (const float*)d_in[13];
    float* out = (float*)d_out;

    // workspace layout (bytes)
    char* ws = (char*)d_ws;
    unsigned short* X    = (unsigned short*)ws;                        // 64 MB
    unsigned short* h1Q  = (unsigned short*)(ws + 67108864);           // 32 MB
    unsigned short* h1V  = (unsigned short*)(ws + 100663296);          // 32 MB
    unsigned short* Qw1t = (unsigned short*)(ws + 134217728);          // 1 MB
    unsigned short* Qw2t = Qw1t + 512 * 1024;
    unsigned short* Vw1t = Qw2t + 512 * 512;
    unsigned short* Vw2t = Vw1t + 512 * 512;

    prep<<<dim3(16960), dim3(256), 0, stream>>>(states, actions, Qw1, Qw2, Vw1, Vw2,
                                                Qb3, Vb3, X, Qw1t, Qw2t, Vw1t, Vw2t, out);

    layer1<<<dim3(512), dim3(512), 0, stream>>>(X, Qw1t, Vw1t, Qb1, Vb1, h1Q, h1V);
    layer2<<<dim3(512), dim3(512), 0, stream>>>(h1Q, h1V, Qw2t, Vw2t, Qb2, Vb2, Qw3, Vw3, out);
}